// Round 14
// baseline (436.104 us; speedup 1.0000x reference)
//
#include <hip/hip_runtime.h>
#include <hip/hip_fp16.h>
#include <math.h>

#define N_NODES 100000
#define N_EDGES 1600000
#define F_DIM 64
#define BSH 9                              // 512 nodes per bucket
#define BNODES 512
#define NBUCK ((N_NODES + BNODES - 1) / BNODES)   // 196
#define CAP 12288                          // slots/bucket (mean 8163, ~45 sigma headroom)
#define EPT 32
#define TILE (256 * EPT)                   // 8192 edges per pass1 block
#define P1B ((N_EDGES + TILE - 1) / TILE)  // 196
#define LINB ((N_NODES + 255) / 256)       // 391
#define GRID (P1B + LINB)                  // 587  (< 1024 resident slots at 4 blocks/CU)

typedef float __attribute__((ext_vector_type(4))) f32x4;

// ---- fused: [pass1 || linear] -> arrive/spin barrier -> passB (blocks 0..NBUCK-1) ----
// Safety: __launch_bounds__(256,4) caps VGPR at 128 -> 4 blocks/CU -> 1024 slots >= 587
// blocks, so ALL blocks are co-resident and the spin barrier cannot deadlock.
__global__ __launch_bounds__(256, 4) void fusedall_k(const int* __restrict__ src,
                                                     const int* __restrict__ dst,
                                                     int* __restrict__ bcur,     // [NBUCK] cursors + [1] done, memset 0
                                                     unsigned int* __restrict__ tmp,
                                                     const float* __restrict__ x,
                                                     const float* __restrict__ W,
                                                     const float* __restrict__ bias,
                                                     __half* __restrict__ h,
                                                     unsigned int* __restrict__ esrc,
                                                     unsigned int* __restrict__ rowinfo,
                                                     float* __restrict__ inv) {
    __shared__ int lcnt[NBUCK];
    __shared__ int lbase[NBUCK];
    __shared__ float Ws[F_DIM][F_DIM];
    __shared__ float bs[F_DIM];
    __shared__ int cnt[BNODES];
    __shared__ int cur[BNODES];
    __shared__ int ls[256];

    const int bid = blockIdx.x;
    const int tid = threadIdx.x;
    int* done = bcur + NBUCK;

    // ================= Phase A =================
    if (bid < P1B) {
        // ---- pass1: bucket scatter ----
        for (int i = tid; i < NBUCK; i += 256) lcnt[i] = 0;
        __syncthreads();

        int4 sreg[EPT / 4], dreg[EPT / 4];
        int base4 = bid * (TILE / 4);
#pragma unroll
        for (int j = 0; j < EPT / 4; ++j) {
            int i4 = base4 + j * 256 + tid;
            if (i4 < N_EDGES / 4) {
                sreg[j] = ((const int4*)src)[i4];
                dreg[j] = ((const int4*)dst)[i4];
                atomicAdd(&lcnt[dreg[j].x >> BSH], 1);
                atomicAdd(&lcnt[dreg[j].y >> BSH], 1);
                atomicAdd(&lcnt[dreg[j].z >> BSH], 1);
                atomicAdd(&lcnt[dreg[j].w >> BSH], 1);
            } else {
                dreg[j].x = -1;
            }
        }
        __syncthreads();
        for (int b = tid; b < NBUCK; b += 256) {
            int c = lcnt[b];
            lbase[b] = c ? atomicAdd(&bcur[b], c) : 0;   // relative base within bucket
            lcnt[b] = 0;
        }
        __syncthreads();
#pragma unroll
        for (int j = 0; j < EPT / 4; ++j) {
            if (dreg[j].x >= 0) {
                int d, s, b, r;
                d = dreg[j].x; s = sreg[j].x; b = d >> BSH;
                r = atomicAdd(&lcnt[b], 1);
                tmp[(size_t)b * CAP + lbase[b] + r] = (unsigned int)s | ((unsigned int)(d & (BNODES - 1)) << 17);
                d = dreg[j].y; s = sreg[j].y; b = d >> BSH;
                r = atomicAdd(&lcnt[b], 1);
                tmp[(size_t)b * CAP + lbase[b] + r] = (unsigned int)s | ((unsigned int)(d & (BNODES - 1)) << 17);
                d = dreg[j].z; s = sreg[j].z; b = d >> BSH;
                r = atomicAdd(&lcnt[b], 1);
                tmp[(size_t)b * CAP + lbase[b] + r] = (unsigned int)s | ((unsigned int)(d & (BNODES - 1)) << 17);
                d = dreg[j].w; s = sreg[j].w; b = d >> BSH;
                r = atomicAdd(&lcnt[b], 1);
                tmp[(size_t)b * CAP + lbase[b] + r] = (unsigned int)s | ((unsigned int)(d & (BNODES - 1)) << 17);
            }
        }
    } else {
        // ---- linear: h = x*W + b (fp16) ----
        for (int i = tid; i < F_DIM * F_DIM; i += 256) Ws[i >> 6][i & 63] = W[i];
        if (tid < F_DIM) bs[tid] = bias[tid];
        __syncthreads();

        int n = (bid - P1B) * 256 + tid;
        if (n < N_NODES) {
            float xr[F_DIM];
            const float4* xp = (const float4*)(x + (size_t)n * F_DIM);
#pragma unroll
            for (int k4 = 0; k4 < 16; ++k4) {
                float4 v = xp[k4];
                xr[k4 * 4 + 0] = v.x; xr[k4 * 4 + 1] = v.y;
                xr[k4 * 4 + 2] = v.z; xr[k4 * 4 + 3] = v.w;
            }
            __half* hp = h + (size_t)n * F_DIM;
#pragma unroll 1
            for (int f0 = 0; f0 < F_DIM; f0 += 4) {
                float a0 = bs[f0 + 0], a1 = bs[f0 + 1], a2 = bs[f0 + 2], a3 = bs[f0 + 3];
#pragma unroll
                for (int k = 0; k < F_DIM; ++k) {
                    float xv = xr[k];
                    a0 += xv * Ws[k][f0 + 0];
                    a1 += xv * Ws[k][f0 + 1];
                    a2 += xv * Ws[k][f0 + 2];
                    a3 += xv * Ws[k][f0 + 3];
                }
                union { __half2 h2[2]; float2 f2; } u;
                u.h2[0] = __floats2half2_rn(a0, a1);
                u.h2[1] = __floats2half2_rn(a2, a3);
                *((float2*)(hp + f0)) = u.f2;
            }
        }
    }

    // ================= arrive / spin barrier =================
    __threadfence();               // release: tmp, bcur, h visible device-wide
    __syncthreads();
    if (tid == 0)
        __hip_atomic_fetch_add(done, 1, __ATOMIC_RELEASE, __HIP_MEMORY_SCOPE_AGENT);

    if (bid >= NBUCK) return;      // non-passB blocks free their slots

    if (tid == 0) {
        while (__hip_atomic_load(done, __ATOMIC_ACQUIRE, __HIP_MEMORY_SCOPE_AGENT) < GRID)
            __builtin_amdgcn_s_sleep(2);
    }
    __syncthreads();
    __threadfence();               // acquire side

    // ================= Phase B: passB for bucket bid =================
    {
        int b = bid;
        int beg0 = b * CAP;
        int cntb = bcur[b];

        cnt[tid] = 0;
        cnt[tid + 256] = 0;
        __syncthreads();
        for (int i = tid; i < cntb; i += 256)
            atomicAdd(&cnt[tmp[beg0 + i] >> 17], 1);
        __syncthreads();

        int a0 = cnt[2 * tid];
        int a1 = cnt[2 * tid + 1];
        int tsum = a0 + a1;
        ls[tid] = tsum;
        __syncthreads();
        for (int off = 1; off < 256; off <<= 1) {
            int p = (tid >= off) ? ls[tid - off] : 0;
            __syncthreads();
            ls[tid] += p;
            __syncthreads();
        }
        int excl = ls[tid] - tsum;
        int p0 = beg0 + excl;
        int p1 = p0 + a0;
        cur[2 * tid] = p0;
        cur[2 * tid + 1] = p1;
        int n0 = (b << BSH) + 2 * tid;
        if (n0 < N_NODES) {
            rowinfo[n0] = (unsigned int)p0 | ((unsigned int)a0 << 22);
            inv[n0] = rsqrtf((float)(a0 + 1));
        }
        if (n0 + 1 < N_NODES) {
            rowinfo[n0 + 1] = (unsigned int)p1 | ((unsigned int)a1 << 22);
            inv[n0 + 1] = rsqrtf((float)(a1 + 1));
        }
        __syncthreads();

        for (int i = tid; i < cntb; i += 256) {
            unsigned int v = tmp[beg0 + i];
            int pos = atomicAdd(&cur[v >> 17], 1);
            esrc[pos] = v & 0x1FFFFu;
        }
    }
}

// ---------------- gelu (tanh approximation, jax.nn.gelu default) ----------------
__device__ __forceinline__ float gelu1(float x) {
    float x3 = x * x * x;
    float t = tanhf(0.7978845608028654f * (x + 0.044715f * x3));
    return 0.5f * x * (1.0f + t);
}

// ---------------- gather: wave/node; 4 edge-slots x 16 lanes (round-11 proven body) ----------------
__global__ __launch_bounds__(256) void gather_k(const __half* __restrict__ h,    // h [N][64]
                                                const float* __restrict__ inv,
                                                const unsigned int* __restrict__ rowinfo,
                                                const unsigned int* __restrict__ esrc,
                                                float* __restrict__ out, int N) {
    int n = blockIdx.x * 4 + (threadIdx.x >> 6);
    if (n >= N) return;
    int lane = threadIdx.x & 63;
    int eslot = lane >> 4;      // 0..3: edge slot
    int fq = lane & 15;         // feature quad (halves 4fq..4fq+3)

    unsigned int ri = rowinfo[n];
    int beg = (int)(ri & 0x3FFFFFu);
    int deg = (int)(ri >> 22);

    float ax = 0.f, ay = 0.f, az = 0.f, aw = 0.f;
    int k = eslot;
    // unroll 4: 16 edges in flight per wave
    for (; k + 12 < deg; k += 16) {
        int s0 = (int)esrc[beg + k];
        int s1 = (int)esrc[beg + k + 4];
        int s2 = (int)esrc[beg + k + 8];
        int s3 = (int)esrc[beg + k + 12];
        float w0 = inv[s0], w1 = inv[s1], w2 = inv[s2], w3 = inv[s3];
        union { float2 f; __half2 h2[2]; } u0, u1, u2, u3;
        u0.f = *((const float2*)(h + (size_t)s0 * F_DIM) + fq);
        u1.f = *((const float2*)(h + (size_t)s1 * F_DIM) + fq);
        u2.f = *((const float2*)(h + (size_t)s2 * F_DIM) + fq);
        u3.f = *((const float2*)(h + (size_t)s3 * F_DIM) + fq);
        float2 a, b;
        a = __half22float2(u0.h2[0]); b = __half22float2(u0.h2[1]);
        ax = fmaf(a.x, w0, ax); ay = fmaf(a.y, w0, ay); az = fmaf(b.x, w0, az); aw = fmaf(b.y, w0, aw);
        a = __half22float2(u1.h2[0]); b = __half22float2(u1.h2[1]);
        ax = fmaf(a.x, w1, ax); ay = fmaf(a.y, w1, ay); az = fmaf(b.x, w1, az); aw = fmaf(b.y, w1, aw);
        a = __half22float2(u2.h2[0]); b = __half22float2(u2.h2[1]);
        ax = fmaf(a.x, w2, ax); ay = fmaf(a.y, w2, ay); az = fmaf(b.x, w2, az); aw = fmaf(b.y, w2, aw);
        a = __half22float2(u3.h2[0]); b = __half22float2(u3.h2[1]);
        ax = fmaf(a.x, w3, ax); ay = fmaf(a.y, w3, ay); az = fmaf(b.x, w3, az); aw = fmaf(b.y, w3, aw);
    }
    for (; k < deg; k += 4) {
        int s0 = (int)esrc[beg + k];
        float w0 = inv[s0];
        union { float2 f; __half2 h2[2]; } u0;
        u0.f = *((const float2*)(h + (size_t)s0 * F_DIM) + fq);
        float2 a = __half22float2(u0.h2[0]);
        float2 b = __half22float2(u0.h2[1]);
        ax = fmaf(a.x, w0, ax); ay = fmaf(a.y, w0, ay); az = fmaf(b.x, w0, az); aw = fmaf(b.y, w0, aw);
    }
    // reduce across the 4 edge slots
    ax += __shfl_xor(ax, 16); ay += __shfl_xor(ay, 16);
    az += __shfl_xor(az, 16); aw += __shfl_xor(aw, 16);
    ax += __shfl_xor(ax, 32); ay += __shfl_xor(ay, 32);
    az += __shfl_xor(az, 32); aw += __shfl_xor(aw, 32);

    if (eslot == 0) {
        float invn = inv[n];
        union { float2 f; __half2 h2[2]; } us;
        us.f = *((const float2*)(h + (size_t)n * F_DIM) + fq);
        float2 s0 = __half22float2(us.h2[0]);
        float2 s1 = __half22float2(us.h2[1]);
        // out = gelu(invn * (sum_e inv[s]h[s] + invn*h[n]))
        float4 o;
        o.x = gelu1((ax + s0.x * invn) * invn);
        o.y = gelu1((ay + s0.y * invn) * invn);
        o.z = gelu1((az + s1.x * invn) * invn);
        o.w = gelu1((aw + s1.y * invn) * invn);
        ((float4*)(out + (size_t)n * F_DIM))[fq] = o;
    }
}

extern "C" void kernel_launch(void* const* d_in, const int* in_sizes, int n_in,
                              void* d_out, int out_size, void* d_ws, size_t ws_size,
                              hipStream_t stream) {
    const float* x    = (const float*)d_in[0];
    const int*   ei   = (const int*)d_in[1];
    const float* W    = (const float*)d_in[2];
    const float* bias = (const float*)d_in[3];
    float* out = (float*)d_out;

    const int* src = ei;             // edge_index[0]
    const int* dst = ei + N_EDGES;   // edge_index[1]

    // workspace (~33 MB)
    unsigned int* tmp     = (unsigned int*)d_ws;              // NBUCK*CAP uints = 9.6 MB
    unsigned int* esrc    = tmp + (size_t)NBUCK * CAP;        // NBUCK*CAP uints = 9.6 MB
    unsigned int* rowinfo = esrc + (size_t)NBUCK * CAP;       // N uints
    float*        inv     = (float*)(rowinfo + N_NODES);      // N floats
    int*          bcur    = (int*)(inv + N_NODES);            // NBUCK ints + 1 done counter
    size_t off = (size_t)(bcur + NBUCK + 1) - (size_t)d_ws;
    off = (off + 31) & ~(size_t)31;
    __half* h = (__half*)((char*)d_ws + off);                 // N*64 halves = 12.8 MB

    hipMemsetAsync(bcur, 0, (NBUCK + 1) * sizeof(int), stream);

    fusedall_k<<<GRID, 256, 0, stream>>>(src, dst, bcur, tmp, x, W, bias, h, esrc, rowinfo, inv);
    gather_k<<<(N_NODES + 3) / 4, 256, 0, stream>>>(h, inv, rowinfo, esrc, out, N_NODES);
}

// Round 15
// 116.550 us; speedup vs baseline: 3.7418x; 3.7418x over previous
//
#include <hip/hip_runtime.h>
#include <hip/hip_fp16.h>
#include <math.h>

#define N_NODES 100000
#define N_EDGES 1600000
#define F_DIM 64
#define BSH 9                              // 512 nodes per bucket
#define BNODES 512
#define NBUCK ((N_NODES + BNODES - 1) / BNODES)   // 196
#define CAP 12288                          // slots/bucket (mean 8163, ~45 sigma headroom)
#define EPT 32
#define TILE (256 * EPT)                   // 8192 edges per pass1 block
#define P1B ((N_EDGES + TILE - 1) / TILE)  // 196
#define LINB ((N_NODES + 255) / 256)       // 391

// ---------------- fused: pass1 (bucket scatter) || linear (h = x*W + b) ----------------
__global__ __launch_bounds__(256) void fused1_k(const int* __restrict__ src,
                                                const int* __restrict__ dst,
                                                int* __restrict__ bcur,            // relative cursors, memset 0
                                                unsigned int* __restrict__ tmp,
                                                const float* __restrict__ x,
                                                const float* __restrict__ W,
                                                const float* __restrict__ bias,
                                                __half* __restrict__ h) {
    if (blockIdx.x < P1B) {
        // ---- pass1 ----
        __shared__ int lcnt[NBUCK];
        __shared__ int lbase[NBUCK];
        for (int i = threadIdx.x; i < NBUCK; i += 256) lcnt[i] = 0;
        __syncthreads();

        int4 sreg[EPT / 4], dreg[EPT / 4];
        int base4 = blockIdx.x * (TILE / 4);
#pragma unroll
        for (int j = 0; j < EPT / 4; ++j) {
            int i4 = base4 + j * 256 + threadIdx.x;
            if (i4 < N_EDGES / 4) {
                sreg[j] = ((const int4*)src)[i4];
                dreg[j] = ((const int4*)dst)[i4];
                atomicAdd(&lcnt[dreg[j].x >> BSH], 1);
                atomicAdd(&lcnt[dreg[j].y >> BSH], 1);
                atomicAdd(&lcnt[dreg[j].z >> BSH], 1);
                atomicAdd(&lcnt[dreg[j].w >> BSH], 1);
            } else {
                dreg[j].x = -1;
            }
        }
        __syncthreads();
        for (int b = threadIdx.x; b < NBUCK; b += 256) {
            int c = lcnt[b];
            lbase[b] = c ? atomicAdd(&bcur[b], c) : 0;   // relative base within bucket
            lcnt[b] = 0;
        }
        __syncthreads();
#pragma unroll
        for (int j = 0; j < EPT / 4; ++j) {
            if (dreg[j].x >= 0) {
                int d, s, b, r;
                d = dreg[j].x; s = sreg[j].x; b = d >> BSH;
                r = atomicAdd(&lcnt[b], 1);
                tmp[(size_t)b * CAP + lbase[b] + r] = (unsigned int)s | ((unsigned int)(d & (BNODES - 1)) << 17);
                d = dreg[j].y; s = sreg[j].y; b = d >> BSH;
                r = atomicAdd(&lcnt[b], 1);
                tmp[(size_t)b * CAP + lbase[b] + r] = (unsigned int)s | ((unsigned int)(d & (BNODES - 1)) << 17);
                d = dreg[j].z; s = sreg[j].z; b = d >> BSH;
                r = atomicAdd(&lcnt[b], 1);
                tmp[(size_t)b * CAP + lbase[b] + r] = (unsigned int)s | ((unsigned int)(d & (BNODES - 1)) << 17);
                d = dreg[j].w; s = sreg[j].w; b = d >> BSH;
                r = atomicAdd(&lcnt[b], 1);
                tmp[(size_t)b * CAP + lbase[b] + r] = (unsigned int)s | ((unsigned int)(d & (BNODES - 1)) << 17);
            }
        }
    } else {
        // ---- linear: h = x*W + b (fp16, no prescale) ----
        __shared__ float Ws[F_DIM][F_DIM];
        __shared__ float bs[F_DIM];
        for (int i = threadIdx.x; i < F_DIM * F_DIM; i += 256) Ws[i >> 6][i & 63] = W[i];
        if (threadIdx.x < F_DIM) bs[threadIdx.x] = bias[threadIdx.x];
        __syncthreads();

        int n = (blockIdx.x - P1B) * 256 + threadIdx.x;
        if (n >= N_NODES) return;

        float xr[F_DIM];
        const float4* xp = (const float4*)(x + (size_t)n * F_DIM);
#pragma unroll
        for (int k4 = 0; k4 < 16; ++k4) {
            float4 v = xp[k4];
            xr[k4 * 4 + 0] = v.x; xr[k4 * 4 + 1] = v.y;
            xr[k4 * 4 + 2] = v.z; xr[k4 * 4 + 3] = v.w;
        }
        __half* hp = h + (size_t)n * F_DIM;
#pragma unroll 1
        for (int f0 = 0; f0 < F_DIM; f0 += 4) {
            float a0 = bs[f0 + 0], a1 = bs[f0 + 1], a2 = bs[f0 + 2], a3 = bs[f0 + 3];
#pragma unroll
            for (int k = 0; k < F_DIM; ++k) {
                float xv = xr[k];
                a0 += xv * Ws[k][f0 + 0];
                a1 += xv * Ws[k][f0 + 1];
                a2 += xv * Ws[k][f0 + 2];
                a3 += xv * Ws[k][f0 + 3];
            }
            union { __half2 h2[2]; float2 f2; } u;
            u.h2[0] = __floats2half2_rn(a0, a1);
            u.h2[1] = __floats2half2_rn(a2, a3);
            *((float2*)(hp + f0)) = u.f2;
        }
    }
}

// ---------------- passB (1024 thr): sort tmp -> esrc (src-range-ordered), rowinfo, inv ----------------
__global__ __launch_bounds__(1024) void passB_k(const unsigned int* __restrict__ tmp,
                                                const int* __restrict__ bcur,      // relative counts
                                                unsigned int* __restrict__ esrc,
                                                unsigned int* __restrict__ rowinfo,
                                                float* __restrict__ inv) {
    __shared__ int cnt[BNODES];
    __shared__ int cur[BNODES];
    __shared__ int ls[BNODES];
    int b = blockIdx.x;
    int tid = threadIdx.x;
    int beg0 = b * CAP;
    int cntb = bcur[b];

    if (tid < BNODES) cnt[tid] = 0;
    __syncthreads();
    for (int i = tid; i < cntb; i += 1024)
        atomicAdd(&cnt[tmp[beg0 + i] >> 17], 1);
    __syncthreads();

    int a = 0;
    if (tid < BNODES) { a = cnt[tid]; ls[tid] = a; }
    __syncthreads();
    for (int off = 1; off < BNODES; off <<= 1) {
        int p = 0;
        if (tid < BNODES && tid >= off) p = ls[tid - off];
        __syncthreads();
        if (tid < BNODES) ls[tid] += p;
        __syncthreads();
    }
    if (tid < BNODES) {
        int p0 = beg0 + ls[tid] - a;
        cur[tid] = p0;
        int n = (b << BSH) + tid;
        if (n < N_NODES) {
            rowinfo[n] = (unsigned int)p0 | ((unsigned int)a << 22);
            inv[n] = rsqrtf((float)(a + 1));
        }
    }
    __syncthreads();

    // 4 sub-passes over src ranges: within each node's segment, edges end up
    // grouped by src>>15 -> concurrent gather waves sweep the h table together,
    // shrinking the instantaneous L2 working set to ~1/4 of the table.
#pragma unroll 1
    for (int c = 0; c < 4; ++c) {
        for (int i = tid; i < cntb; i += 1024) {
            unsigned int v = tmp[beg0 + i];
            unsigned int s = v & 0x1FFFFu;
            if ((s >> 15) == (unsigned int)c) {
                int pos = atomicAdd(&cur[v >> 17], 1);
                esrc[pos] = s;
            }
        }
    }
}

// ---------------- gelu (tanh approximation, jax.nn.gelu default) ----------------
__device__ __forceinline__ float gelu1(float x) {
    float x3 = x * x * x;
    float t = tanhf(0.7978845608028654f * (x + 0.044715f * x3));
    return 0.5f * x * (1.0f + t);
}

// ---------------- gather: wave/node; 4 edge-slots x 16 lanes (round-11 proven body) ----------------
__global__ __launch_bounds__(256) void gather_k(const __half* __restrict__ h,    // h [N][64]
                                                const float* __restrict__ inv,
                                                const unsigned int* __restrict__ rowinfo,
                                                const unsigned int* __restrict__ esrc,
                                                float* __restrict__ out, int N) {
    int n = blockIdx.x * 4 + (threadIdx.x >> 6);
    if (n >= N) return;
    int lane = threadIdx.x & 63;
    int eslot = lane >> 4;      // 0..3: edge slot
    int fq = lane & 15;         // feature quad (halves 4fq..4fq+3)

    unsigned int ri = rowinfo[n];
    int beg = (int)(ri & 0x3FFFFFu);
    int deg = (int)(ri >> 22);

    float ax = 0.f, ay = 0.f, az = 0.f, aw = 0.f;
    int k = eslot;
    // unroll 4: 16 edges in flight per wave
    for (; k + 12 < deg; k += 16) {
        int s0 = (int)esrc[beg + k];
        int s1 = (int)esrc[beg + k + 4];
        int s2 = (int)esrc[beg + k + 8];
        int s3 = (int)esrc[beg + k + 12];
        float w0 = inv[s0], w1 = inv[s1], w2 = inv[s2], w3 = inv[s3];
        union { float2 f; __half2 h2[2]; } u0, u1, u2, u3;
        u0.f = *((const float2*)(h + (size_t)s0 * F_DIM) + fq);
        u1.f = *((const float2*)(h + (size_t)s1 * F_DIM) + fq);
        u2.f = *((const float2*)(h + (size_t)s2 * F_DIM) + fq);
        u3.f = *((const float2*)(h + (size_t)s3 * F_DIM) + fq);
        float2 a, b;
        a = __half22float2(u0.h2[0]); b = __half22float2(u0.h2[1]);
        ax = fmaf(a.x, w0, ax); ay = fmaf(a.y, w0, ay); az = fmaf(b.x, w0, az); aw = fmaf(b.y, w0, aw);
        a = __half22float2(u1.h2[0]); b = __half22float2(u1.h2[1]);
        ax = fmaf(a.x, w1, ax); ay = fmaf(a.y, w1, ay); az = fmaf(b.x, w1, az); aw = fmaf(b.y, w1, aw);
        a = __half22float2(u2.h2[0]); b = __half22float2(u2.h2[1]);
        ax = fmaf(a.x, w2, ax); ay = fmaf(a.y, w2, ay); az = fmaf(b.x, w2, az); aw = fmaf(b.y, w2, aw);
        a = __half22float2(u3.h2[0]); b = __half22float2(u3.h2[1]);
        ax = fmaf(a.x, w3, ax); ay = fmaf(a.y, w3, ay); az = fmaf(b.x, w3, az); aw = fmaf(b.y, w3, aw);
    }
    for (; k < deg; k += 4) {
        int s0 = (int)esrc[beg + k];
        float w0 = inv[s0];
        union { float2 f; __half2 h2[2]; } u0;
        u0.f = *((const float2*)(h + (size_t)s0 * F_DIM) + fq);
        float2 a = __half22float2(u0.h2[0]);
        float2 b = __half22float2(u0.h2[1]);
        ax = fmaf(a.x, w0, ax); ay = fmaf(a.y, w0, ay); az = fmaf(b.x, w0, az); aw = fmaf(b.y, w0, aw);
    }
    // reduce across the 4 edge slots
    ax += __shfl_xor(ax, 16); ay += __shfl_xor(ay, 16);
    az += __shfl_xor(az, 16); aw += __shfl_xor(aw, 16);
    ax += __shfl_xor(ax, 32); ay += __shfl_xor(ay, 32);
    az += __shfl_xor(az, 32); aw += __shfl_xor(aw, 32);

    if (eslot == 0) {
        float invn = inv[n];
        union { float2 f; __half2 h2[2]; } us;
        us.f = *((const float2*)(h + (size_t)n * F_DIM) + fq);
        float2 s0 = __half22float2(us.h2[0]);
        float2 s1 = __half22float2(us.h2[1]);
        // out = gelu(invn * (sum_e inv[s]h[s] + invn*h[n]))
        float4 o;
        o.x = gelu1((ax + s0.x * invn) * invn);
        o.y = gelu1((ay + s0.y * invn) * invn);
        o.z = gelu1((az + s1.x * invn) * invn);
        o.w = gelu1((aw + s1.y * invn) * invn);
        ((float4*)(out + (size_t)n * F_DIM))[fq] = o;
    }
}

extern "C" void kernel_launch(void* const* d_in, const int* in_sizes, int n_in,
                              void* d_out, int out_size, void* d_ws, size_t ws_size,
                              hipStream_t stream) {
    const float* x    = (const float*)d_in[0];
    const int*   ei   = (const int*)d_in[1];
    const float* W    = (const float*)d_in[2];
    const float* bias = (const float*)d_in[3];
    float* out = (float*)d_out;

    const int* src = ei;             // edge_index[0]
    const int* dst = ei + N_EDGES;   // edge_index[1]

    // workspace (~33 MB)
    unsigned int* tmp     = (unsigned int*)d_ws;              // NBUCK*CAP uints = 9.6 MB
    unsigned int* esrc    = tmp + (size_t)NBUCK * CAP;        // NBUCK*CAP uints = 9.6 MB
    unsigned int* rowinfo = esrc + (size_t)NBUCK * CAP;       // N uints
    float*        inv     = (float*)(rowinfo + N_NODES);      // N floats
    int*          bcur    = (int*)(inv + N_NODES);            // NBUCK ints
    size_t off = (size_t)(bcur + NBUCK) - (size_t)d_ws;
    off = (off + 31) & ~(size_t)31;
    __half* h = (__half*)((char*)d_ws + off);                 // N*64 halves = 12.8 MB

    hipMemsetAsync(bcur, 0, NBUCK * sizeof(int), stream);

    fused1_k<<<P1B + LINB, 256, 0, stream>>>(src, dst, bcur, tmp, x, W, bias, h);
    passB_k<<<NBUCK, 1024, 0, stream>>>(tmp, bcur, esrc, rowinfo, inv);
    gather_k<<<(N_NODES + 3) / 4, 256, 0, stream>>>(h, inv, rowinfo, esrc, out, N_NODES);
}

// Round 16
// 113.940 us; speedup vs baseline: 3.8275x; 1.0229x over previous
//
#include <hip/hip_runtime.h>
#include <hip/hip_fp16.h>
#include <math.h>

#define N_NODES 100000
#define N_EDGES 1600000
#define F_DIM 64
#define BSH 9                              // 512 nodes per bucket
#define BNODES 512
#define NBUCK ((N_NODES + BNODES - 1) / BNODES)   // 196
#define CAP 12288                          // slots/bucket (mean 8163, ~45 sigma headroom)
#define EPT 32
#define TILE (256 * EPT)                   // 8192 edges per pass1 block
#define P1B ((N_EDGES + TILE - 1) / TILE)  // 196
#define LINB ((N_NODES + 255) / 256)       // 391

// ---------------- fused: pass1 (bucket scatter) || linear (h = x*W + b) ----------------
__global__ __launch_bounds__(256) void fused1_k(const int* __restrict__ src,
                                                const int* __restrict__ dst,
                                                int* __restrict__ bcur,            // relative cursors, memset 0
                                                unsigned int* __restrict__ tmp,
                                                const float* __restrict__ x,
                                                const float* __restrict__ W,
                                                const float* __restrict__ bias,
                                                __half* __restrict__ h) {
    if (blockIdx.x < P1B) {
        // ---- pass1 ----
        __shared__ int lcnt[NBUCK];
        __shared__ int lbase[NBUCK];
        for (int i = threadIdx.x; i < NBUCK; i += 256) lcnt[i] = 0;
        __syncthreads();

        int4 sreg[EPT / 4], dreg[EPT / 4];
        int base4 = blockIdx.x * (TILE / 4);
#pragma unroll
        for (int j = 0; j < EPT / 4; ++j) {
            int i4 = base4 + j * 256 + threadIdx.x;
            if (i4 < N_EDGES / 4) {
                sreg[j] = ((const int4*)src)[i4];
                dreg[j] = ((const int4*)dst)[i4];
                atomicAdd(&lcnt[dreg[j].x >> BSH], 1);
                atomicAdd(&lcnt[dreg[j].y >> BSH], 1);
                atomicAdd(&lcnt[dreg[j].z >> BSH], 1);
                atomicAdd(&lcnt[dreg[j].w >> BSH], 1);
            } else {
                dreg[j].x = -1;
            }
        }
        __syncthreads();
        for (int b = threadIdx.x; b < NBUCK; b += 256) {
            int c = lcnt[b];
            lbase[b] = c ? atomicAdd(&bcur[b], c) : 0;   // relative base within bucket
            lcnt[b] = 0;
        }
        __syncthreads();
#pragma unroll
        for (int j = 0; j < EPT / 4; ++j) {
            if (dreg[j].x >= 0) {
                int d, s, b, r;
                d = dreg[j].x; s = sreg[j].x; b = d >> BSH;
                r = atomicAdd(&lcnt[b], 1);
                tmp[(size_t)b * CAP + lbase[b] + r] = (unsigned int)s | ((unsigned int)(d & (BNODES - 1)) << 17);
                d = dreg[j].y; s = sreg[j].y; b = d >> BSH;
                r = atomicAdd(&lcnt[b], 1);
                tmp[(size_t)b * CAP + lbase[b] + r] = (unsigned int)s | ((unsigned int)(d & (BNODES - 1)) << 17);
                d = dreg[j].z; s = sreg[j].z; b = d >> BSH;
                r = atomicAdd(&lcnt[b], 1);
                tmp[(size_t)b * CAP + lbase[b] + r] = (unsigned int)s | ((unsigned int)(d & (BNODES - 1)) << 17);
                d = dreg[j].w; s = sreg[j].w; b = d >> BSH;
                r = atomicAdd(&lcnt[b], 1);
                tmp[(size_t)b * CAP + lbase[b] + r] = (unsigned int)s | ((unsigned int)(d & (BNODES - 1)) << 17);
            }
        }
    } else {
        // ---- linear: h = x*W + b (fp16, no prescale) ----
        __shared__ float Ws[F_DIM][F_DIM];
        __shared__ float bs[F_DIM];
        for (int i = threadIdx.x; i < F_DIM * F_DIM; i += 256) Ws[i >> 6][i & 63] = W[i];
        if (threadIdx.x < F_DIM) bs[threadIdx.x] = bias[threadIdx.x];
        __syncthreads();

        int n = (blockIdx.x - P1B) * 256 + threadIdx.x;
        if (n >= N_NODES) return;

        float xr[F_DIM];
        const float4* xp = (const float4*)(x + (size_t)n * F_DIM);
#pragma unroll
        for (int k4 = 0; k4 < 16; ++k4) {
            float4 v = xp[k4];
            xr[k4 * 4 + 0] = v.x; xr[k4 * 4 + 1] = v.y;
            xr[k4 * 4 + 2] = v.z; xr[k4 * 4 + 3] = v.w;
        }
        __half* hp = h + (size_t)n * F_DIM;
#pragma unroll 1
        for (int f0 = 0; f0 < F_DIM; f0 += 4) {
            float a0 = bs[f0 + 0], a1 = bs[f0 + 1], a2 = bs[f0 + 2], a3 = bs[f0 + 3];
#pragma unroll
            for (int k = 0; k < F_DIM; ++k) {
                float xv = xr[k];
                a0 += xv * Ws[k][f0 + 0];
                a1 += xv * Ws[k][f0 + 1];
                a2 += xv * Ws[k][f0 + 2];
                a3 += xv * Ws[k][f0 + 3];
            }
            union { __half2 h2[2]; float2 f2; } u;
            u.h2[0] = __floats2half2_rn(a0, a1);
            u.h2[1] = __floats2half2_rn(a2, a3);
            *((float2*)(hp + f0)) = u.f2;
        }
    }
}

// ---------------- passB (1024 thr, no LDS staging): sort tmp -> esrc, rowinfo, inv ----------------
__global__ __launch_bounds__(1024) void passB_k(const unsigned int* __restrict__ tmp,
                                                const int* __restrict__ bcur,      // relative counts
                                                unsigned int* __restrict__ esrc,
                                                unsigned int* __restrict__ rowinfo,
                                                float* __restrict__ inv) {
    __shared__ int cnt[BNODES];
    __shared__ int cur[BNODES];
    __shared__ int ls[BNODES];
    int b = blockIdx.x;
    int tid = threadIdx.x;
    int beg0 = b * CAP;
    int cntb = bcur[b];

    if (tid < BNODES) cnt[tid] = 0;
    __syncthreads();
    for (int i = tid; i < cntb; i += 1024)
        atomicAdd(&cnt[tmp[beg0 + i] >> 17], 1);
    __syncthreads();

    int a = 0;
    if (tid < BNODES) { a = cnt[tid]; ls[tid] = a; }
    __syncthreads();
    for (int off = 1; off < BNODES; off <<= 1) {
        int p = 0;
        if (tid < BNODES && tid >= off) p = ls[tid - off];
        __syncthreads();
        if (tid < BNODES) ls[tid] += p;
        __syncthreads();
    }
    if (tid < BNODES) {
        int p0 = beg0 + ls[tid] - a;
        cur[tid] = p0;
        int n = (b << BSH) + tid;
        if (n < N_NODES) {
            rowinfo[n] = (unsigned int)p0 | ((unsigned int)a << 22);
            inv[n] = rsqrtf((float)(a + 1));
        }
    }
    __syncthreads();

    for (int i = tid; i < cntb; i += 1024) {
        unsigned int v = tmp[beg0 + i];
        int pos = atomicAdd(&cur[v >> 17], 1);
        esrc[pos] = v & 0x1FFFFu;
    }
}

// ---------------- gelu (tanh approximation, jax.nn.gelu default) ----------------
__device__ __forceinline__ float gelu1(float x) {
    float x3 = x * x * x;
    float t = tanhf(0.7978845608028654f * (x + 0.044715f * x3));
    return 0.5f * x * (1.0f + t);
}

// ---------------- gather: wave/node; 4 edge-slots x 16 lanes; inv[s] per edge ----------------
__global__ __launch_bounds__(256) void gather_k(const __half* __restrict__ h,    // h [N][64]
                                                const float* __restrict__ inv,
                                                const unsigned int* __restrict__ rowinfo,
                                                const unsigned int* __restrict__ esrc,
                                                float* __restrict__ out, int N) {
    int n = blockIdx.x * 4 + (threadIdx.x >> 6);
    if (n >= N) return;
    int lane = threadIdx.x & 63;
    int eslot = lane >> 4;      // 0..3: edge slot
    int fq = lane & 15;         // feature quad (halves 4fq..4fq+3)

    unsigned int ri = rowinfo[n];
    int beg = (int)(ri & 0x3FFFFFu);
    int deg = (int)(ri >> 22);

    float ax = 0.f, ay = 0.f, az = 0.f, aw = 0.f;
    int k = eslot;
    // unroll 4: 16 edges in flight per wave
    for (; k + 12 < deg; k += 16) {
        int s0 = (int)esrc[beg + k];
        int s1 = (int)esrc[beg + k + 4];
        int s2 = (int)esrc[beg + k + 8];
        int s3 = (int)esrc[beg + k + 12];
        float w0 = inv[s0], w1 = inv[s1], w2 = inv[s2], w3 = inv[s3];
        union { float2 f; __half2 h2[2]; } u0, u1, u2, u3;
        u0.f = *((const float2*)(h + (size_t)s0 * F_DIM) + fq);
        u1.f = *((const float2*)(h + (size_t)s1 * F_DIM) + fq);
        u2.f = *((const float2*)(h + (size_t)s2 * F_DIM) + fq);
        u3.f = *((const float2*)(h + (size_t)s3 * F_DIM) + fq);
        float2 a, b;
        a = __half22float2(u0.h2[0]); b = __half22float2(u0.h2[1]);
        ax = fmaf(a.x, w0, ax); ay = fmaf(a.y, w0, ay); az = fmaf(b.x, w0, az); aw = fmaf(b.y, w0, aw);
        a = __half22float2(u1.h2[0]); b = __half22float2(u1.h2[1]);
        ax = fmaf(a.x, w1, ax); ay = fmaf(a.y, w1, ay); az = fmaf(b.x, w1, az); aw = fmaf(b.y, w1, aw);
        a = __half22float2(u2.h2[0]); b = __half22float2(u2.h2[1]);
        ax = fmaf(a.x, w2, ax); ay = fmaf(a.y, w2, ay); az = fmaf(b.x, w2, az); aw = fmaf(b.y, w2, aw);
        a = __half22float2(u3.h2[0]); b = __half22float2(u3.h2[1]);
        ax = fmaf(a.x, w3, ax); ay = fmaf(a.y, w3, ay); az = fmaf(b.x, w3, az); aw = fmaf(b.y, w3, aw);
    }
    for (; k < deg; k += 4) {
        int s0 = (int)esrc[beg + k];
        float w0 = inv[s0];
        union { float2 f; __half2 h2[2]; } u0;
        u0.f = *((const float2*)(h + (size_t)s0 * F_DIM) + fq);
        float2 a = __half22float2(u0.h2[0]);
        float2 b = __half22float2(u0.h2[1]);
        ax = fmaf(a.x, w0, ax); ay = fmaf(a.y, w0, ay); az = fmaf(b.x, w0, az); aw = fmaf(b.y, w0, aw);
    }
    // reduce across the 4 edge slots
    ax += __shfl_xor(ax, 16); ay += __shfl_xor(ay, 16);
    az += __shfl_xor(az, 16); aw += __shfl_xor(aw, 16);
    ax += __shfl_xor(ax, 32); ay += __shfl_xor(ay, 32);
    az += __shfl_xor(az, 32); aw += __shfl_xor(aw, 32);

    if (eslot == 0) {
        float invn = inv[n];
        union { float2 f; __half2 h2[2]; } us;
        us.f = *((const float2*)(h + (size_t)n * F_DIM) + fq);
        float2 s0 = __half22float2(us.h2[0]);
        float2 s1 = __half22float2(us.h2[1]);
        // out = gelu(invn * (sum_e inv[s]h[s] + invn*h[n]))
        float4 o;
        o.x = gelu1((ax + s0.x * invn) * invn);
        o.y = gelu1((ay + s0.y * invn) * invn);
        o.z = gelu1((az + s1.x * invn) * invn);
        o.w = gelu1((aw + s1.y * invn) * invn);
        ((float4*)(out + (size_t)n * F_DIM))[fq] = o;
    }
}

extern "C" void kernel_launch(void* const* d_in, const int* in_sizes, int n_in,
                              void* d_out, int out_size, void* d_ws, size_t ws_size,
                              hipStream_t stream) {
    const float* x    = (const float*)d_in[0];
    const int*   ei   = (const int*)d_in[1];
    const float* W    = (const float*)d_in[2];
    const float* bias = (const float*)d_in[3];
    float* out = (float*)d_out;

    const int* src = ei;             // edge_index[0]
    const int* dst = ei + N_EDGES;   // edge_index[1]

    // workspace (~33 MB)
    unsigned int* tmp     = (unsigned int*)d_ws;              // NBUCK*CAP uints = 9.6 MB
    unsigned int* esrc    = tmp + (size_t)NBUCK * CAP;        // NBUCK*CAP uints = 9.6 MB
    unsigned int* rowinfo = esrc + (size_t)NBUCK * CAP;       // N uints
    float*        inv     = (float*)(rowinfo + N_NODES);      // N floats
    int*          bcur    = (int*)(inv + N_NODES);            // NBUCK ints
    size_t off = (size_t)(bcur + NBUCK) - (size_t)d_ws;
    off = (off + 31) & ~(size_t)31;
    __half* h = (__half*)((char*)d_ws + off);                 // N*64 halves = 12.8 MB

    hipMemsetAsync(bcur, 0, NBUCK * sizeof(int), stream);

    fused1_k<<<P1B + LINB, 256, 0, stream>>>(src, dst, bcur, tmp, x, W, bias, h);
    passB_k<<<NBUCK, 1024, 0, stream>>>(tmp, bcur, esrc, rowinfo, inv);
    gather_k<<<(N_NODES + 3) / 4, 256, 0, stream>>>(h, inv, rowinfo, esrc, out, N_NODES);
}